// Round 21
// baseline (612.833 us; speedup 1.0000x reference)
//
#include <hip/hip_runtime.h>

// EdgeConv: B=4, C=64, N=8192, K=16, COUT=64, fp32.
// ws layout (27.6 MB; grid scratch aliased onto mxb, cpack onto mnb):
//   xt     : 0         (8388608)   x transposed to (B,N,C)
//   knn    : 8388608   (2097152)
//   mnb    : 10485760  (8388608)   [cpack aliases here until edge]
//   mxb    : 18874368  (8388608)   [grid scratch aliases here until edge]
//     spos4   : 18874368 (524288)   cell-sorted (x,y,z,sq)
//     cstart  : 19398656 (526336)   per-batch cell offsets
//     cursor  : 19924992 (526336)   scatter cursors
//     cells   : 20451328 (131072)   per-point cell id
//     partials: 20582400 (256)      scan chunk sums
//     sidx    : 20582656 (131072)   per-slot original index
//     bbox    : 20713728 (2048)     per-512-block min/max (2 float4 each)
//     wbox    : 20715776 (32768)    per-32-slot-window min/max (2 float4 each)
//   ps1    : 27262976  (131072)
//   ps2    : 27394048  (131072)
//   stats  : 27525120  (512)

#define Bn 4
#define Nn 8192
#define Gc 32
#define CS 32896
#define Hc 0.375f

typedef unsigned long long ull;

__device__ __forceinline__ int cellof(float v) {
  int i = (int)floorf((v + 6.0f) * (1.0f / Hc));
  return min(Gc - 1, max(0, i));
}

// ------- transpose x (B,C,N) -> xt (B,N,C); pack coords -> (x,y,z,sq) -------
__global__ __launch_bounds__(256) void transpose_kernel(const float* __restrict__ x,
                                                        const float* __restrict__ coords,
                                                        float* __restrict__ xt,
                                                        float4* __restrict__ cpack) {
  __shared__ float tile[64][65];
  int bid = blockIdx.x;
  int b = bid >> 7;
  int n0 = (bid & 127) << 6;
  int tx = threadIdx.x & 63;
  int ty = threadIdx.x >> 6;
  for (int c = ty; c < 64; c += 4)
    tile[tx][c] = x[((size_t)b * 64 + c) * Nn + n0 + tx];
  if (ty == 0) {
    int n = n0 + tx;
    const float* cb = coords + (size_t)b * 3 * Nn;
    float cx = cb[n], cy = cb[Nn + n], cz = cb[2 * Nn + n];
    // sq exactly as np.sum(ct*ct,-1): ((x*x + y*y) + z*z), no FMA
    float cs = __fadd_rn(__fadd_rn(__fmul_rn(cx, cx), __fmul_rn(cy, cy)),
                         __fmul_rn(cz, cz));
    cpack[(size_t)b * Nn + n] = make_float4(cx, cy, cz, cs);
  }
  __syncthreads();
  for (int r = ty; r < 64; r += 4)
    xt[((size_t)b * Nn + n0 + r) * 64 + tx] = tile[r][tx];
}

// ---------------- grid build (proven): hist -> scan -> scatter ----------------
__global__ __launch_bounds__(256) void hist_kernel(const float4* __restrict__ cpack,
                                                   unsigned* __restrict__ cells,
                                                   unsigned* __restrict__ cstart) {
  int n = blockIdx.x * 256 + threadIdx.x;
  float4 c = cpack[n];
  unsigned cell = ((unsigned)cellof(c.z) * Gc + cellof(c.y)) * Gc + cellof(c.x);
  cells[n] = cell;
  atomicAdd(&cstart[(unsigned)(n >> 13) * CS + cell], 1u);
}

__global__ __launch_bounds__(256) void scanA_kernel(unsigned* __restrict__ cstart,
                                                    unsigned* __restrict__ partials) {
  __shared__ unsigned sums[256];
  int bid = blockIdx.x, b = bid >> 4, ch = bid & 15, t = threadIdx.x;
  unsigned* base = cstart + (size_t)b * CS + ch * 2048 + t * 8;
  unsigned v[8], p = 0;
#pragma unroll
  for (int j = 0; j < 8; ++j) { unsigned c = base[j]; v[j] = p; p += c; }
  sums[t] = p;
  __syncthreads();
  for (int off = 1; off < 256; off <<= 1) {
    unsigned u = (t >= off) ? sums[t - off] : 0u;
    __syncthreads();
    sums[t] += u;
    __syncthreads();
  }
  unsigned excl = sums[t] - p;
#pragma unroll
  for (int j = 0; j < 8; ++j) base[j] = v[j] + excl;
  if (t == 255) partials[bid] = sums[255];
}

__global__ __launch_bounds__(256) void scanC_kernel(unsigned* __restrict__ cstart,
                                                    unsigned* __restrict__ cursor,
                                                    const unsigned* __restrict__ partials) {
  int bid = blockIdx.x, b = bid >> 4, ch = bid & 15, t = threadIdx.x;
  unsigned off = 0;
  for (int k = 0; k < ch; ++k) off += partials[b * 16 + k];
  size_t o = (size_t)b * CS + ch * 2048 + t * 8;
#pragma unroll
  for (int j = 0; j < 8; ++j) {
    unsigned val = cstart[o + j] + off;
    cstart[o + j] = val;
    cursor[o + j] = val;
  }
}

__global__ __launch_bounds__(256) void scatter_kernel(const float4* __restrict__ cpack,
                                                      const unsigned* __restrict__ cells,
                                                      unsigned* __restrict__ cursor,
                                                      float4* __restrict__ spos4,
                                                      unsigned* __restrict__ sidx) {
  int n = blockIdx.x * 256 + threadIdx.x;
  int b = n >> 13;
  unsigned slot = atomicAdd(&cursor[(size_t)b * CS + cells[n]], 1u);
  spos4[(size_t)b * Nn + slot] = cpack[n];        // keeps exact sq in .w
  sidx[(size_t)b * Nn + slot] = (unsigned)(n & 8191);
}

// -------- per-512-block bounding boxes (exact min/max of scattered coords) --------
__global__ __launch_bounds__(256) void bbox_kernel(const float4* __restrict__ spos4,
                                                   float4* __restrict__ bbox) {
  __shared__ float4 smn[256], smx[256];
  int blk = blockIdx.x;                 // 0..63 : b = blk>>4, m = blk&15
  int t = threadIdx.x;
  const float4* sp = spos4 + (size_t)(blk >> 4) * Nn + (blk & 15) * 512;
  float4 a = sp[t], c = sp[t + 256];
  smn[t] = make_float4(fminf(a.x, c.x), fminf(a.y, c.y), fminf(a.z, c.z), 0.f);
  smx[t] = make_float4(fmaxf(a.x, c.x), fmaxf(a.y, c.y), fmaxf(a.z, c.z), 0.f);
  __syncthreads();
  for (int off = 128; off > 0; off >>= 1) {
    if (t < off) {
      float4 n2 = smn[t + off], x2 = smx[t + off], n1 = smn[t], x1 = smx[t];
      smn[t] = make_float4(fminf(n1.x, n2.x), fminf(n1.y, n2.y), fminf(n1.z, n2.z), 0.f);
      smx[t] = make_float4(fmaxf(x1.x, x2.x), fmaxf(x1.y, x2.y), fmaxf(x1.z, x2.z), 0.f);
    }
    __syncthreads();
  }
  if (t == 0) { bbox[blk * 2] = smn[0]; bbox[blk * 2 + 1] = smx[0]; }
}

// -------- per-32-slot-window bounding boxes (1024 windows, 1 wave each) --------
__global__ __launch_bounds__(64) void wbox_kernel(const float4* __restrict__ spos4,
                                                  float4* __restrict__ wbox) {
  int w = blockIdx.x;                   // 0..1023 : b = w>>8, window = w&255
  int t = threadIdx.x & 31;             // lanes l and l+32 duplicate slot l
  float4 c = spos4[(size_t)(w >> 8) * Nn + (w & 255) * 32 + t];
  float mnx = c.x, mny = c.y, mnz = c.z;
  float mxx = c.x, mxy = c.y, mxz = c.z;
#pragma unroll
  for (int m = 16; m >= 1; m >>= 1) {
    mnx = fminf(mnx, __shfl_xor(mnx, m));
    mny = fminf(mny, __shfl_xor(mny, m));
    mnz = fminf(mnz, __shfl_xor(mnz, m));
    mxx = fmaxf(mxx, __shfl_xor(mxx, m));
    mxy = fmaxf(mxy, __shfl_xor(mxy, m));
    mxz = fmaxf(mxz, __shfl_xor(mxz, m));
  }
  if (threadIdx.x == 0) {
    wbox[w * 2]     = make_float4(mnx, mny, mnz, 0.f);
    wbox[w * 2 + 1] = make_float4(mxx, mxy, mxz, 0.f);
  }
}

// ---- KNN: barrier-free scan (r18) + WAVE-UNIFORM 32-slot WINDOW bbox skip ----
// Wave s owns windows {s, s+4, s+8, s+12} of each visited block; lanes l and
// l+32 serve the SAME query (q = lane&31) on candidate halves 0-15 / 16-31,
// so window-skip verdicts are identical across all 64 lanes -> __all(skip)
// is a uniform branch skipping the whole 16-candidate mask pass + flush.
// Skip valid: thr_hi = min(sthr[q], local slice 16th) >= final global 16th
// (subset-16th >= global-16th; sthr monotone conservative); ref-d2 >=
// dmin2(wbox) - 4e-5, margin 1e-3 -> skipped windows hold no top-16 member.
// Coverage: 16 windows x 2 lane-halves = all 512 slots, each tested once per
// query. Exact d2 / u64 keys / sorted output unchanged -> selection
// bit-identical to r13/r15/r18.
#define RMAX(kv) do {                                         \
    ull _kk = (kv);                                           \
    _Pragma("unroll")                                         \
    for (int _u = 0; _u < 16; ++_u)                           \
      ad[_u] = (ad[_u] == thr) ? _kk : ad[_u];                \
    ull _t0 = ad[0] > ad[1] ? ad[0] : ad[1];                  \
    ull _t1 = ad[2] > ad[3] ? ad[2] : ad[3];                  \
    ull _t2 = ad[4] > ad[5] ? ad[4] : ad[5];                  \
    ull _t3 = ad[6] > ad[7] ? ad[6] : ad[7];                  \
    ull _t4 = ad[8] > ad[9] ? ad[8] : ad[9];                  \
    ull _t5 = ad[10] > ad[11] ? ad[10] : ad[11];              \
    ull _t6 = ad[12] > ad[13] ? ad[12] : ad[13];              \
    ull _t7 = ad[14] > ad[15] ? ad[14] : ad[15];              \
    ull _u0 = _t0 > _t1 ? _t0 : _t1;                          \
    ull _u1 = _t2 > _t3 ? _t2 : _t3;                          \
    ull _u2 = _t4 > _t5 ? _t4 : _t5;                          \
    ull _u3 = _t6 > _t7 ? _t6 : _t7;                          \
    ull _v0 = _u0 > _u1 ? _u0 : _u1;                          \
    ull _v1 = _u2 > _u3 ? _u2 : _u3;                          \
    thr = _v0 > _v1 ? _v0 : _v1;                              \
  } while (0)

#define SINS(kv) do {                                         \
    ull _kk = (kv);                                           \
    if (_kk < nad[15]) {                                      \
      bool _ci = true;                                        \
      _Pragma("unroll")                                       \
      for (int _u = 15; _u >= 1; --_u) {                      \
        bool _cm = _kk < nad[_u - 1];                         \
        nad[_u] = _ci ? (_cm ? nad[_u - 1] : _kk) : nad[_u];  \
        _ci = _cm;                                            \
      }                                                       \
      nad[0] = _ci ? _kk : nad[0];                            \
    }                                                         \
  } while (0)

__global__ __launch_bounds__(256) void knn_kernel(const float4* __restrict__ spos4,
                                                  const unsigned* __restrict__ sidx,
                                                  const float4* __restrict__ bbox,
                                                  const float4* __restrict__ wbox,
                                                  int* __restrict__ knn) {
  __shared__ __align__(16) ull mk[7 * 16 * 32];   // 28672 B (merge rows)
  __shared__ unsigned sthr[32];

  int bid = blockIdx.x;
  int b = bid >> 8;                        // 1024 blocks = 4 batches x 256
  int grp = bid & 255;                     // 32-query group within batch
  int tid = threadIdx.x;
  int lane = tid & 63;
  int l32 = lane & 31;
  int hh = lane >> 5;                      // candidate half 0/1
  int s = tid >> 6;                        // wave 0..3
  int qslot = grp * 32 + l32;

  const float4* sp = spos4 + (size_t)b * Nn;
  const unsigned* sx = sidx + (size_t)b * Nn;

  float4 qc = sp[qslot];
  unsigned qg = sx[qslot];
  float qs = qc.w;
  float qx2 = 2.f * qc.x, qy2 = 2.f * qc.y, qz2 = 2.f * qc.z;

  if (tid < 32) sthr[tid] = 0xFFFFFFFFu;
  __syncthreads();                         // sthr init visible

  ull ad[16];
#pragma unroll
  for (int i = 0; i < 16; ++i) ad[i] = 0xFFFFFFFF00000000ull | (unsigned)i;
  ull thr = 0xFFFFFFFF0000000Full;
  unsigned thr_hi = 0xFFFFFFFFu;

  // zigzag over 512-slot blocks around the group's own block; waves independent
  int m0 = grp >> 4;
  int visited = 0;
  for (int step = 0; step < 32 && visited < 16; ++step) {
    int d = (step + 1) >> 1;
    int m = (step & 1) ? (m0 + d) : (m0 - d);
    if (m < 0 || m >= 16) continue;
    ++visited;

    // ---- block-level bbox skip (verdicts identical across all 64 lanes) ----
    {
      unsigned sh = sthr[l32];
      thr_hi = sh < thr_hi ? sh : thr_hi;
      float4 bmn = bbox[(b * 16 + m) * 2];
      float4 bmx = bbox[(b * 16 + m) * 2 + 1];
      float ddx = fmaxf(fmaxf(bmn.x - qc.x, qc.x - bmx.x), 0.f);
      float ddy = fmaxf(fmaxf(bmn.y - qc.y, qc.y - bmx.y), 0.f);
      float ddz = fmaxf(fmaxf(bmn.z - qc.z, qc.z - bmx.z), 0.f);
      float dmin2 = ddx * ddx + ddy * ddy + ddz * ddz;
      // NaN thr_hi compares false -> never skips before thresholds are real
      int skipl = (dmin2 > __uint_as_float(thr_hi) + 1e-3f) ? 1 : 0;
      if (__all(skipl)) continue;
    }

    int mbase = m * 512;
#pragma unroll
    for (int wi = 0; wi < 4; ++wi) {
      int widx = s + wi * 4;               // wave-uniform window 0..15
      // ---- window-level bbox skip ----
      const float4* wb = wbox + (size_t)((b * 256 + (m << 4) + widx) << 1);
      float4 wmn = wb[0], wmx = wb[1];
      float ex = fmaxf(fmaxf(wmn.x - qc.x, qc.x - wmx.x), 0.f);
      float ey = fmaxf(fmaxf(wmn.y - qc.y, qc.y - wmx.y), 0.f);
      float ez = fmaxf(fmaxf(wmn.z - qc.z, qc.z - wmx.z), 0.f);
      float wd2 = ex * ex + ey * ey + ez * ez;
      unsigned sh = sthr[l32];
      thr_hi = sh < thr_hi ? sh : thr_hi;
      int wskip = (wd2 > __uint_as_float(thr_hi) + 1e-3f) ? 1 : 0;
      if (__all(wskip)) continue;          // uniform: lanes l, l+32 same query

      int base = mbase + widx * 32 + hh * 16;   // this lane-half's 16 slots
      const float4* cpb = sp + base;
      const unsigned* sxb = sx + base;
      unsigned mask = 0;
#pragma unroll
      for (int j = 0; j < 16; ++j) {
        float4 c4 = cpb[j];                // broadcast global load (L2-hit)
        float dot2 = __fadd_rn(__fadd_rn(__fmul_rn(qx2, c4.x), __fmul_rn(qy2, c4.y)),
                               __fmul_rn(qz2, c4.z));
        float d2 = __fsub_rn(__fadd_rn(qs, c4.w), dot2);
        mask |= (__float_as_uint(d2) <= thr_hi) ? (1u << j) : 0u;
      }
      // exclude self by slot position (falls in exactly one half-window)
      unsigned sj = (unsigned)(qslot - base);
      if (sj < 16u) mask &= ~(1u << sj);
      // wave-synchronized rescan flush (re-reads are L1-hits)
      while (__any(mask)) {
        if (mask) {
          int j = __ffs(mask) - 1;
          mask &= (mask - 1);
          float4 c4 = cpb[j];
          float dot2 = __fadd_rn(__fadd_rn(__fmul_rn(qx2, c4.x), __fmul_rn(qy2, c4.y)),
                                 __fmul_rn(qz2, c4.z));
          float d2 = __fsub_rn(__fadd_rn(qs, c4.w), dot2);
          ull key = ((ull)__float_as_uint(d2) << 32) | sxb[j];
          if (key < thr) RMAX(key);
        }
      }
      unsigned lh = (unsigned)(thr >> 32);
      thr_hi = lh < thr_hi ? lh : thr_hi;
      atomicMin(&sthr[l32], lh);           // no barrier needed (conservative)
    }
  }

  // ---- merge the 8 (wave x half) slices per query ----
  __syncthreads();                          // all waves done scanning
  if (lane >= 32) {                         // half-1 slices -> rows 0,2,4,6
    int row = 2 * s;
#pragma unroll
    for (int i = 0; i < 16; ++i) mk[(row * 16 + i) * 32 + l32] = ad[i];
  } else if (s > 0) {                       // half-0 of waves 1..3 -> rows 1,3,5
    int row = 2 * s - 1;
#pragma unroll
    for (int i = 0; i < 16; ++i) mk[(row * 16 + i) * 32 + l32] = ad[i];
  }
  __syncthreads();
  if (s == 0 && lane < 32) {
    ull nad[16];
#pragma unroll
    for (int i = 0; i < 16; ++i) nad[i] = ~0ull;
#pragma unroll
    for (int i = 0; i < 16; ++i) SINS(ad[i]);
    for (int t = 0; t < 7 * 16; ++t) SINS(mk[t * 32 + l32]);
    int* op = knn + (size_t)(b * Nn + (int)qg) * 16;
#pragma unroll
    for (int i = 0; i < 16; ++i) op[i] = (int)(nad[i] & 0xFFFFFFFFull);
  }
}

// ---------------- edge features + GEMM + minmax + channel sums ----------------
// VERBATIM r14/r15/r18.
__global__ __launch_bounds__(256, 2) void edge_kernel(
    const float* __restrict__ xt, const int* __restrict__ knn,
    const float* __restrict__ W, const float* __restrict__ bias,
    float* __restrict__ mnb, float* __restrict__ mxb,
    float* __restrict__ ps1, float* __restrict__ ps2) {
  __shared__ float dlds[4][16][64];
  __shared__ float clds[4][64];
  __shared__ float r1[4][64], r2[4][64];

  int tid = threadIdx.x;
  int l = tid & 63;
  int w = tid >> 6;

  float w1[64], w2[64];
#pragma unroll
  for (int c = 0; c < 64; ++c) {
    w1[c] = W[c * 64 + l];
    w2[c] = W[(64 + c) * 64 + l];
  }
  float bl = bias[l];
  float s1 = 0.f, s2 = 0.f;

  int wid = blockIdx.x * 4 + w;
  int nw = gridDim.x * 4;
  for (int p = wid; p < Bn * Nn; p += nw) {
    int bb = p >> 13;
    const float* xb = xt + (size_t)bb * Nn * 64;
    float ctr = xt[(size_t)p * 64 + l];
    clds[w][l] = ctr;
    const int* ip = knn + (size_t)p * 16;
#pragma unroll
    for (int j = 0; j < 16; ++j) {
      int nj = ip[j];
      dlds[w][j][l] = xb[(size_t)nj * 64 + l] - ctr;
    }
    __syncthreads();

    const float4* cv = (const float4*)clds[w];
    float cc = bl;
#pragma unroll
    for (int c = 0; c < 16; ++c) {
      float4 v = cv[c];
      cc = fmaf(v.w, w1[4 * c + 3], fmaf(v.z, w1[4 * c + 2],
           fmaf(v.y, w1[4 * c + 1], fmaf(v.x, w1[4 * c + 0], cc))));
    }

    float mn = 3.0e38f, mx = -3.0e38f;
#pragma unroll
    for (int k = 0; k < 16; ++k) {
      const float4* dv = (const float4*)dlds[w][k];
      float h = cc;
#pragma unroll
      for (int c = 0; c < 16; ++c) {
        float4 v = dv[c];
        h = fmaf(v.w, w2[4 * c + 3], fmaf(v.z, w2[4 * c + 2],
            fmaf(v.y, w2[4 * c + 1], fmaf(v.x, w2[4 * c + 0], h))));
      }
      mn = fminf(mn, h);
      mx = fmaxf(mx, h);
      s1 += h;
      s2 = fmaf(h, h, s2);
    }
    mnb[(size_t)p * 64 + l] = mn;
    mxb[(size_t)p * 64 + l] = mx;
    __syncthreads();
  }

  r1[w][l] = s1; r2[w][l] = s2;
  __syncthreads();
  if (w == 0) {
    float a = r1[0][l] + r1[1][l] + r1[2][l] + r1[3][l];
    float c2 = r2[0][l] + r2[1][l] + r2[2][l] + r2[3][l];
    ps1[blockIdx.x * 64 + l] = a;
    ps2[blockIdx.x * 64 + l] = c2;
  }
}

// ---------------- deterministic stats reduction ----------------
__global__ __launch_bounds__(256) void stats_kernel(const float* __restrict__ ps1,
                                                    const float* __restrict__ ps2,
                                                    float* __restrict__ stats) {
  __shared__ float r1[4][64], r2[4][64];
  int c = threadIdx.x & 63, g = threadIdx.x >> 6;
  float a = 0.f, b2 = 0.f;
  for (int i = g; i < 512; i += 4) { a += ps1[i * 64 + c]; b2 += ps2[i * 64 + c]; }
  r1[g][c] = a; r2[g][c] = b2;
  __syncthreads();
  if (g == 0) {
    float s1 = r1[0][c] + r1[1][c] + r1[2][c] + r1[3][c];
    float s2 = r2[0][c] + r2[1][c] + r2[2][c] + r2[3][c];
    const float invM = 1.f / 524288.f;
    float mean = s1 * invM;
    float var = s2 * invM - mean * mean;
    stats[c] = mean;
    stats[64 + c] = var;
  }
}

// ---------------- finalize: normalize+relu+max_k, transposed store ----------------
__global__ __launch_bounds__(256) void final_kernel(
    const float* __restrict__ mnb, const float* __restrict__ mxb,
    const float* __restrict__ stats, const float* __restrict__ gamma,
    const float* __restrict__ beta, float* __restrict__ out) {
  __shared__ float tile[64][65];
  int bid = blockIdx.x;
  int b = bid >> 7;
  int n0 = (bid & 127) << 6;
  int tx = threadIdx.x & 63, ty = threadIdx.x >> 6;
  float mean = stats[tx], var = stats[64 + tx];
  float sc = gamma[tx] * rsqrtf(var + 1e-5f);
  float sh = fmaf(-mean, sc, beta[tx]);
  for (int r = ty; r < 64; r += 4) {
    size_t off = ((size_t)(b * Nn + n0 + r)) * 64 + tx;
    float lo = fmaf(mnb[off], sc, sh);
    float hi = fmaf(mxb[off], sc, sh);
    tile[tx][r] = fmaxf(fmaxf(hi, lo), 0.f);
  }
  __syncthreads();
  for (int r = ty; r < 64; r += 4)
    out[((size_t)b * 64 + r) * Nn + n0 + tx] = tile[r][tx];
}

extern "C" void kernel_launch(void* const* d_in, const int* in_sizes, int n_in,
                              void* d_out, int out_size, void* d_ws, size_t ws_size,
                              hipStream_t stream) {
  const float* x      = (const float*)d_in[0];
  const float* coords = (const float*)d_in[1];
  const float* W      = (const float*)d_in[2];
  const float* bias   = (const float*)d_in[3];
  const float* gamma  = (const float*)d_in[4];
  const float* beta   = (const float*)d_in[5];
  float* out = (float*)d_out;

  char* ws = (char*)d_ws;
  float*    xt       = (float*)ws;
  int*      knn      = (int*)(ws + 8388608);
  float*    mnb      = (float*)(ws + 10485760);
  float4*   cpack    = (float4*)(ws + 10485760);   // aliases mnb
  float*    mxb      = (float*)(ws + 18874368);
  float4*   spos4    = (float4*)(ws + 18874368);   // aliases mxb region
  unsigned* cstart   = (unsigned*)(ws + 19398656);
  unsigned* cursor   = (unsigned*)(ws + 19924992);
  unsigned* cells    = (unsigned*)(ws + 20451328);
  unsigned* partials = (unsigned*)(ws + 20582400);
  unsigned* sidx     = (unsigned*)(ws + 20582656);
  float4*   bbox     = (float4*)(ws + 20713728);
  float4*   wbox     = (float4*)(ws + 20715776);
  float*    ps1      = (float*)(ws + 27262976);
  float*    ps2      = (float*)(ws + 27394048);
  float*    stats    = (float*)(ws + 27525120);

  transpose_kernel<<<dim3(512), dim3(256), 0, stream>>>(x, coords, xt, cpack);
  hipMemsetAsync(cstart, 0, (size_t)4 * CS * 4, stream);
  hist_kernel<<<dim3(128), dim3(256), 0, stream>>>(cpack, cells, cstart);
  scanA_kernel<<<dim3(64), dim3(256), 0, stream>>>(cstart, partials);
  scanC_kernel<<<dim3(64), dim3(256), 0, stream>>>(cstart, cursor, partials);
  scatter_kernel<<<dim3(128), dim3(256), 0, stream>>>(cpack, cells, cursor, spos4, sidx);
  bbox_kernel<<<dim3(64), dim3(256), 0, stream>>>(spos4, bbox);
  wbox_kernel<<<dim3(1024), dim3(64), 0, stream>>>(spos4, wbox);
  knn_kernel<<<dim3(1024), dim3(256), 0, stream>>>(spos4, sidx, bbox, wbox, knn);
  edge_kernel<<<dim3(512), dim3(256), 0, stream>>>(xt, knn, W, bias, mnb, mxb, ps1, ps2);
  stats_kernel<<<dim3(1), dim3(256), 0, stream>>>(ps1, ps2, stats);
  final_kernel<<<dim3(512), dim3(256), 0, stream>>>(mnb, mxb, stats, gamma, beta, out);
}

// Round 22
// 568.703 us; speedup vs baseline: 1.0776x; 1.0776x over previous
//
#include <hip/hip_runtime.h>

// EdgeConv: B=4, C=64, N=8192, K=16, COUT=64, fp32.
// ws layout (27.6 MB; grid scratch aliased onto mxb, cpack onto mnb):
//   xt     : 0         (8388608)   x transposed to (B,N,C)
//   knn    : 8388608   (2097152)
//   mnb    : 10485760  (8388608)   [cpack aliases here until edge]
//   mxb    : 18874368  (8388608)   [grid scratch aliases here until edge]
//     spos4   : 18874368 (524288)   cell-sorted (x,y,z,sq)
//     cstart  : 19398656 (526336)   per-batch cell offsets
//     cursor  : 19924992 (526336)   scatter cursors
//     cells   : 20451328 (131072)   per-point cell id
//     partials: 20582400 (256)      scan chunk sums
//     sidx    : 20582656 (131072)   per-slot original index
//     bbox    : 20713728 (2048)     per-512-block min/max (2 float4 each)
//   ps1    : 27262976  (131072)
//   ps2    : 27394048  (131072)
//   stats  : 27525120  (512)

#define Bn 4
#define Nn 8192
#define Gc 32
#define CS 32896
#define Hc 0.375f

typedef unsigned long long ull;

__device__ __forceinline__ int cellof(float v) {
  int i = (int)floorf((v + 6.0f) * (1.0f / Hc));
  return min(Gc - 1, max(0, i));
}

// ------- transpose x (B,C,N) -> xt (B,N,C); pack coords -> (x,y,z,sq) -------
__global__ __launch_bounds__(256) void transpose_kernel(const float* __restrict__ x,
                                                        const float* __restrict__ coords,
                                                        float* __restrict__ xt,
                                                        float4* __restrict__ cpack) {
  __shared__ float tile[64][65];
  int bid = blockIdx.x;
  int b = bid >> 7;
  int n0 = (bid & 127) << 6;
  int tx = threadIdx.x & 63;
  int ty = threadIdx.x >> 6;
  for (int c = ty; c < 64; c += 4)
    tile[tx][c] = x[((size_t)b * 64 + c) * Nn + n0 + tx];
  if (ty == 0) {
    int n = n0 + tx;
    const float* cb = coords + (size_t)b * 3 * Nn;
    float cx = cb[n], cy = cb[Nn + n], cz = cb[2 * Nn + n];
    // sq exactly as np.sum(ct*ct,-1): ((x*x + y*y) + z*z), no FMA
    float cs = __fadd_rn(__fadd_rn(__fmul_rn(cx, cx), __fmul_rn(cy, cy)),
                         __fmul_rn(cz, cz));
    cpack[(size_t)b * Nn + n] = make_float4(cx, cy, cz, cs);
  }
  __syncthreads();
  for (int r = ty; r < 64; r += 4)
    xt[((size_t)b * Nn + n0 + r) * 64 + tx] = tile[r][tx];
}

// ---------------- grid build (proven): hist -> scan -> scatter ----------------
__global__ __launch_bounds__(256) void hist_kernel(const float4* __restrict__ cpack,
                                                   unsigned* __restrict__ cells,
                                                   unsigned* __restrict__ cstart) {
  int n = blockIdx.x * 256 + threadIdx.x;
  float4 c = cpack[n];
  unsigned cell = ((unsigned)cellof(c.z) * Gc + cellof(c.y)) * Gc + cellof(c.x);
  cells[n] = cell;
  atomicAdd(&cstart[(unsigned)(n >> 13) * CS + cell], 1u);
}

__global__ __launch_bounds__(256) void scanA_kernel(unsigned* __restrict__ cstart,
                                                    unsigned* __restrict__ partials) {
  __shared__ unsigned sums[256];
  int bid = blockIdx.x, b = bid >> 4, ch = bid & 15, t = threadIdx.x;
  unsigned* base = cstart + (size_t)b * CS + ch * 2048 + t * 8;
  unsigned v[8], p = 0;
#pragma unroll
  for (int j = 0; j < 8; ++j) { unsigned c = base[j]; v[j] = p; p += c; }
  sums[t] = p;
  __syncthreads();
  for (int off = 1; off < 256; off <<= 1) {
    unsigned u = (t >= off) ? sums[t - off] : 0u;
    __syncthreads();
    sums[t] += u;
    __syncthreads();
  }
  unsigned excl = sums[t] - p;
#pragma unroll
  for (int j = 0; j < 8; ++j) base[j] = v[j] + excl;
  if (t == 255) partials[bid] = sums[255];
}

__global__ __launch_bounds__(256) void scanC_kernel(unsigned* __restrict__ cstart,
                                                    unsigned* __restrict__ cursor,
                                                    const unsigned* __restrict__ partials) {
  int bid = blockIdx.x, b = bid >> 4, ch = bid & 15, t = threadIdx.x;
  unsigned off = 0;
  for (int k = 0; k < ch; ++k) off += partials[b * 16 + k];
  size_t o = (size_t)b * CS + ch * 2048 + t * 8;
#pragma unroll
  for (int j = 0; j < 8; ++j) {
    unsigned val = cstart[o + j] + off;
    cstart[o + j] = val;
    cursor[o + j] = val;
  }
}

__global__ __launch_bounds__(256) void scatter_kernel(const float4* __restrict__ cpack,
                                                      const unsigned* __restrict__ cells,
                                                      unsigned* __restrict__ cursor,
                                                      float4* __restrict__ spos4,
                                                      unsigned* __restrict__ sidx) {
  int n = blockIdx.x * 256 + threadIdx.x;
  int b = n >> 13;
  unsigned slot = atomicAdd(&cursor[(size_t)b * CS + cells[n]], 1u);
  spos4[(size_t)b * Nn + slot] = cpack[n];        // keeps exact sq in .w
  sidx[(size_t)b * Nn + slot] = (unsigned)(n & 8191);
}

// -------- per-512-block bounding boxes (exact min/max of scattered coords) --------
__global__ __launch_bounds__(256) void bbox_kernel(const float4* __restrict__ spos4,
                                                   float4* __restrict__ bbox) {
  __shared__ float4 smn[256], smx[256];
  int blk = blockIdx.x;                 // 0..63 : b = blk>>4, m = blk&15
  int t = threadIdx.x;
  const float4* sp = spos4 + (size_t)(blk >> 4) * Nn + (blk & 15) * 512;
  float4 a = sp[t], c = sp[t + 256];
  smn[t] = make_float4(fminf(a.x, c.x), fminf(a.y, c.y), fminf(a.z, c.z), 0.f);
  smx[t] = make_float4(fmaxf(a.x, c.x), fmaxf(a.y, c.y), fmaxf(a.z, c.z), 0.f);
  __syncthreads();
  for (int off = 128; off > 0; off >>= 1) {
    if (t < off) {
      float4 n2 = smn[t + off], x2 = smx[t + off], n1 = smn[t], x1 = smx[t];
      smn[t] = make_float4(fminf(n1.x, n2.x), fminf(n1.y, n2.y), fminf(n1.z, n2.z), 0.f);
      smx[t] = make_float4(fmaxf(x1.x, x2.x), fmaxf(x1.y, x2.y), fmaxf(x1.z, x2.z), 0.f);
    }
    __syncthreads();
  }
  if (t == 0) { bbox[blk * 2] = smn[0]; bbox[blk * 2 + 1] = smx[0]; }
}

// ---- KNN: BARRIER-FREE scan (r18-proven). Candidates read directly from
// global (L2-hit broadcast within each half-wave) -- no LDS stage, no
// per-round barriers. Waves scan independently; sthr (LDS atomicMin) needs
// no barrier: every read is a conservative upper bound >= final 16th
// (monotone, timing-independent). bbox skip is per-wave. Exact d2 / u64
// keys / sorted output -> deterministic, matches reference selection.
#define RMAX(kv) do {                                         \
    ull _kk = (kv);                                           \
    _Pragma("unroll")                                         \
    for (int _u = 0; _u < 16; ++_u)                           \
      ad[_u] = (ad[_u] == thr) ? _kk : ad[_u];                \
    ull _t0 = ad[0] > ad[1] ? ad[0] : ad[1];                  \
    ull _t1 = ad[2] > ad[3] ? ad[2] : ad[3];                  \
    ull _t2 = ad[4] > ad[5] ? ad[4] : ad[5];                  \
    ull _t3 = ad[6] > ad[7] ? ad[6] : ad[7];                  \
    ull _t4 = ad[8] > ad[9] ? ad[8] : ad[9];                  \
    ull _t5 = ad[10] > ad[11] ? ad[10] : ad[11];              \
    ull _t6 = ad[12] > ad[13] ? ad[12] : ad[13];              \
    ull _t7 = ad[14] > ad[15] ? ad[14] : ad[15];              \
    ull _u0 = _t0 > _t1 ? _t0 : _t1;                          \
    ull _u1 = _t2 > _t3 ? _t2 : _t3;                          \
    ull _u2 = _t4 > _t5 ? _t4 : _t5;                          \
    ull _u3 = _t6 > _t7 ? _t6 : _t7;                          \
    ull _v0 = _u0 > _u1 ? _u0 : _u1;                          \
    ull _v1 = _u2 > _u3 ? _u2 : _u3;                          \
    thr = _v0 > _v1 ? _v0 : _v1;                              \
  } while (0)

#define SINS(kv) do {                                         \
    ull _kk = (kv);                                           \
    if (_kk < nad[15]) {                                      \
      bool _ci = true;                                        \
      _Pragma("unroll")                                       \
      for (int _u = 15; _u >= 1; --_u) {                      \
        bool _cm = _kk < nad[_u - 1];                         \
        nad[_u] = _ci ? (_cm ? nad[_u - 1] : _kk) : nad[_u];  \
        _ci = _cm;                                            \
      }                                                       \
      nad[0] = _ci ? _kk : nad[0];                            \
    }                                                         \
  } while (0)

__global__ __launch_bounds__(256) void knn_kernel(const float4* __restrict__ spos4,
                                                  const unsigned* __restrict__ sidx,
                                                  const float4* __restrict__ bbox,
                                                  int* __restrict__ knn) {
  __shared__ __align__(16) ull mk[7 * 16 * 32];   // 28672 B (merge rows)
  __shared__ unsigned sthr[32];

  int bid = blockIdx.x;
  int b = bid >> 8;                        // 1024 blocks = 4 batches x 256
  int grp = bid & 255;                     // 32-query group within batch
  int tid = threadIdx.x;
  int lane = tid & 63;
  int l32 = lane & 31;
  int s = tid >> 6;                        // wave 0..3
  int ss = (s << 1) | (lane >> 5);         // slice 0..7 (wave x lane-half)
  int qslot = grp * 32 + l32;

  const float4* sp = spos4 + (size_t)b * Nn;
  const unsigned* sx = sidx + (size_t)b * Nn;

  float4 qc = sp[qslot];
  unsigned qg = sx[qslot];
  float qs = qc.w;
  float qx2 = 2.f * qc.x, qy2 = 2.f * qc.y, qz2 = 2.f * qc.z;

  if (tid < 32) sthr[tid] = 0xFFFFFFFFu;
  __syncthreads();                         // sthr init visible; last block sync
                                           // until the merge phase

  ull ad[16];
#pragma unroll
  for (int i = 0; i < 16; ++i) ad[i] = 0xFFFFFFFF00000000ull | (unsigned)i;
  ull thr = 0xFFFFFFFF0000000Full;
  unsigned thr_hi = 0xFFFFFFFFu;

  // zigzag over 512-slot blocks around the group's own block; waves proceed
  // independently (no intra-round barriers).
  int m0 = grp >> 4;
  int visited = 0;
  for (int step = 0; step < 32 && visited < 16; ++step) {
    int d = (step + 1) >> 1;
    int m = (step & 1) ? (m0 + d) : (m0 - d);
    if (m < 0 || m >= 16) continue;
    ++visited;

    // ---- per-wave bbox skip (lane verdicts identical across half-waves) ----
    float4 bmn = bbox[(b * 16 + m) * 2];
    float4 bmx = bbox[(b * 16 + m) * 2 + 1];
    float ddx = fmaxf(fmaxf(bmn.x - qc.x, qc.x - bmx.x), 0.f);
    float ddy = fmaxf(fmaxf(bmn.y - qc.y, qc.y - bmx.y), 0.f);
    float ddz = fmaxf(fmaxf(bmn.z - qc.z, qc.z - bmx.z), 0.f);
    float dmin2 = ddx * ddx + ddy * ddy + ddz * ddz;
    unsigned shu = sthr[l32];
    // NaN-init compares false -> never skips before thresholds are real
    int skipl = (dmin2 > __uint_as_float(shu) + 1e-3f) ? 1 : 0;
    if (__all(skipl)) continue;

    int loc0 = m * 512 + ss * 32;          // this half-wave's windows: loc0, loc0+256
#pragma unroll
    for (int half = 0; half < 2; ++half) {
      int base = loc0 + half * 256;
      const float4* cpb = sp + base;
      const unsigned* sxb = sx + base;
      unsigned sh = sthr[l32];
      thr_hi = sh < thr_hi ? sh : thr_hi;
      unsigned mask = 0;
#pragma unroll 8
      for (int j = 0; j < 32; ++j) {
        float4 c4 = cpb[j];                // broadcast global load (L2-hit)
        float dot2 = __fadd_rn(__fadd_rn(__fmul_rn(qx2, c4.x), __fmul_rn(qy2, c4.y)),
                               __fmul_rn(qz2, c4.z));
        float d2 = __fsub_rn(__fadd_rn(qs, c4.w), dot2);
        mask |= (__float_as_uint(d2) <= thr_hi) ? (1u << j) : 0u;
      }
      // exclude self by slot position (falls in exactly one window)
      unsigned sj = (unsigned)(qslot - base);
      if (sj < 32u) mask &= ~(1u << sj);
      // wave-synchronized rescan flush (re-reads are L1-hits)
      while (__any(mask)) {
        if (mask) {
          int j = __ffs(mask) - 1;
          mask &= (mask - 1);
          float4 c4 = cpb[j];
          float dot2 = __fadd_rn(__fadd_rn(__fmul_rn(qx2, c4.x), __fmul_rn(qy2, c4.y)),
                                 __fmul_rn(qz2, c4.z));
          float d2 = __fsub_rn(__fadd_rn(qs, c4.w), dot2);
          ull key = ((ull)__float_as_uint(d2) << 32) | sxb[j];
          if (key < thr) RMAX(key);
        }
      }
      unsigned lh = (unsigned)(thr >> 32);
      thr_hi = lh < thr_hi ? lh : thr_hi;
      atomicMin(&sthr[l32], lh);           // no barrier needed (conservative)
    }
  }

  // ---- merge the 8 slices per query ----
  __syncthreads();                          // all waves done scanning
  if (lane >= 32) {                         // slices 1,3,5,7 -> rows 0,2,4,6
    int row = 2 * s;
#pragma unroll
    for (int i = 0; i < 16; ++i) mk[(row * 16 + i) * 32 + l32] = ad[i];
  } else if (s > 0) {                       // slices 2,4,6 -> rows 1,3,5
    int row = 2 * s - 1;
#pragma unroll
    for (int i = 0; i < 16; ++i) mk[(row * 16 + i) * 32 + l32] = ad[i];
  }
  __syncthreads();
  if (s == 0 && lane < 32) {
    ull nad[16];
#pragma unroll
    for (int i = 0; i < 16; ++i) nad[i] = ~0ull;
#pragma unroll
    for (int i = 0; i < 16; ++i) SINS(ad[i]);
    for (int t = 0; t < 7 * 16; ++t) SINS(mk[t * 32 + l32]);
    int* op = knn + (size_t)(b * Nn + (int)qg) * 16;
#pragma unroll
    for (int i = 0; i < 16; ++i) op[i] = (int)(nad[i] & 0xFFFFFFFFull);
  }
}

// ---------------- edge features + GEMM + minmax + channel sums ----------------
// VERBATIM r14/r15/r18.
__global__ __launch_bounds__(256, 2) void edge_kernel(
    const float* __restrict__ xt, const int* __restrict__ knn,
    const float* __restrict__ W, const float* __restrict__ bias,
    float* __restrict__ mnb, float* __restrict__ mxb,
    float* __restrict__ ps1, float* __restrict__ ps2) {
  __shared__ float dlds[4][16][64];
  __shared__ float clds[4][64];
  __shared__ float r1[4][64], r2[4][64];

  int tid = threadIdx.x;
  int l = tid & 63;
  int w = tid >> 6;

  float w1[64], w2[64];
#pragma unroll
  for (int c = 0; c < 64; ++c) {
    w1[c] = W[c * 64 + l];
    w2[c] = W[(64 + c) * 64 + l];
  }
  float bl = bias[l];
  float s1 = 0.f, s2 = 0.f;

  int wid = blockIdx.x * 4 + w;
  int nw = gridDim.x * 4;
  for (int p = wid; p < Bn * Nn; p += nw) {
    int bb = p >> 13;
    const float* xb = xt + (size_t)bb * Nn * 64;
    float ctr = xt[(size_t)p * 64 + l];
    clds[w][l] = ctr;
    const int* ip = knn + (size_t)p * 16;
#pragma unroll
    for (int j = 0; j < 16; ++j) {
      int nj = ip[j];
      dlds[w][j][l] = xb[(size_t)nj * 64 + l] - ctr;
    }
    __syncthreads();

    const float4* cv = (const float4*)clds[w];
    float cc = bl;
#pragma unroll
    for (int c = 0; c < 16; ++c) {
      float4 v = cv[c];
      cc = fmaf(v.w, w1[4 * c + 3], fmaf(v.z, w1[4 * c + 2],
           fmaf(v.y, w1[4 * c + 1], fmaf(v.x, w1[4 * c + 0], cc))));
    }

    float mn = 3.0e38f, mx = -3.0e38f;
#pragma unroll
    for (int k = 0; k < 16; ++k) {
      const float4* dv = (const float4*)dlds[w][k];
      float h = cc;
#pragma unroll
      for (int c = 0; c < 16; ++c) {
        float4 v = dv[c];
        h = fmaf(v.w, w2[4 * c + 3], fmaf(v.z, w2[4 * c + 2],
            fmaf(v.y, w2[4 * c + 1], fmaf(v.x, w2[4 * c + 0], h))));
      }
      mn = fminf(mn, h);
      mx = fmaxf(mx, h);
      s1 += h;
      s2 = fmaf(h, h, s2);
    }
    mnb[(size_t)p * 64 + l] = mn;
    mxb[(size_t)p * 64 + l] = mx;
    __syncthreads();
  }

  r1[w][l] = s1; r2[w][l] = s2;
  __syncthreads();
  if (w == 0) {
    float a = r1[0][l] + r1[1][l] + r1[2][l] + r1[3][l];
    float c2 = r2[0][l] + r2[1][l] + r2[2][l] + r2[3][l];
    ps1[blockIdx.x * 64 + l] = a;
    ps2[blockIdx.x * 64 + l] = c2;
  }
}

// ---------------- deterministic stats reduction ----------------
__global__ __launch_bounds__(256) void stats_kernel(const float* __restrict__ ps1,
                                                    const float* __restrict__ ps2,
                                                    float* __restrict__ stats) {
  __shared__ float r1[4][64], r2[4][64];
  int c = threadIdx.x & 63, g = threadIdx.x >> 6;
  float a = 0.f, b2 = 0.f;
  for (int i = g; i < 512; i += 4) { a += ps1[i * 64 + c]; b2 += ps2[i * 64 + c]; }
  r1[g][c] = a; r2[g][c] = b2;
  __syncthreads();
  if (g == 0) {
    float s1 = r1[0][c] + r1[1][c] + r1[2][c] + r1[3][c];
    float s2 = r2[0][c] + r2[1][c] + r2[2][c] + r2[3][c];
    const float invM = 1.f / 524288.f;
    float mean = s1 * invM;
    float var = s2 * invM - mean * mean;
    stats[c] = mean;
    stats[64 + c] = var;
  }
}

// ---------------- finalize: normalize+relu+max_k, transposed store ----------------
__global__ __launch_bounds__(256) void final_kernel(
    const float* __restrict__ mnb, const float* __restrict__ mxb,
    const float* __restrict__ stats, const float* __restrict__ gamma,
    const float* __restrict__ beta, float* __restrict__ out) {
  __shared__ float tile[64][65];
  int bid = blockIdx.x;
  int b = bid >> 7;
  int n0 = (bid & 127) << 6;
  int tx = threadIdx.x & 63, ty = threadIdx.x >> 6;
  float mean = stats[tx], var = stats[64 + tx];
  float sc = gamma[tx] * rsqrtf(var + 1e-5f);
  float sh = fmaf(-mean, sc, beta[tx]);
  for (int r = ty; r < 64; r += 4) {
    size_t off = ((size_t)(b * Nn + n0 + r)) * 64 + tx;
    float lo = fmaf(mnb[off], sc, sh);
    float hi = fmaf(mxb[off], sc, sh);
    tile[tx][r] = fmaxf(fmaxf(hi, lo), 0.f);
  }
  __syncthreads();
  for (int r = ty; r < 64; r += 4)
    out[((size_t)b * 64 + r) * Nn + n0 + tx] = tile[r][tx];
}

extern "C" void kernel_launch(void* const* d_in, const int* in_sizes, int n_in,
                              void* d_out, int out_size, void* d_ws, size_t ws_size,
                              hipStream_t stream) {
  const float* x      = (const float*)d_in[0];
  const float* coords = (const float*)d_in[1];
  const float* W      = (const float*)d_in[2];
  const float* bias   = (const float*)d_in[3];
  const float* gamma  = (const float*)d_in[4];
  const float* beta   = (const float*)d_in[5];
  float* out = (float*)d_out;

  char* ws = (char*)d_ws;
  float*    xt       = (float*)ws;
  int*      knn      = (int*)(ws + 8388608);
  float*    mnb      = (float*)(ws + 10485760);
  float4*   cpack    = (float4*)(ws + 10485760);   // aliases mnb
  float*    mxb      = (float*)(ws + 18874368);
  float4*   spos4    = (float4*)(ws + 18874368);   // aliases mxb region
  unsigned* cstart   = (unsigned*)(ws + 19398656);
  unsigned* cursor   = (unsigned*)(ws + 19924992);
  unsigned* cells    = (unsigned*)(ws + 20451328);
  unsigned* partials = (unsigned*)(ws + 20582400);
  unsigned* sidx     = (unsigned*)(ws + 20582656);
  float4*   bbox     = (float4*)(ws + 20713728);
  float*    ps1      = (float*)(ws + 27262976);
  float*    ps2      = (float*)(ws + 27394048);
  float*    stats    = (float*)(ws + 27525120);

  transpose_kernel<<<dim3(512), dim3(256), 0, stream>>>(x, coords, xt, cpack);
  hipMemsetAsync(cstart, 0, (size_t)4 * CS * 4, stream);
  hist_kernel<<<dim3(128), dim3(256), 0, stream>>>(cpack, cells, cstart);
  scanA_kernel<<<dim3(64), dim3(256), 0, stream>>>(cstart, partials);
  scanC_kernel<<<dim3(64), dim3(256), 0, stream>>>(cstart, cursor, partials);
  scatter_kernel<<<dim3(128), dim3(256), 0, stream>>>(cpack, cells, cursor, spos4, sidx);
  bbox_kernel<<<dim3(64), dim3(256), 0, stream>>>(spos4, bbox);
  knn_kernel<<<dim3(1024), dim3(256), 0, stream>>>(spos4, sidx, bbox, knn);
  edge_kernel<<<dim3(512), dim3(256), 0, stream>>>(xt, knn, W, bias, mnb, mxb, ps1, ps2);
  stats_kernel<<<dim3(1), dim3(256), 0, stream>>>(ps1, ps2, stats);
  final_kernel<<<dim3(512), dim3(256), 0, stream>>>(mnb, mxb, stats, gamma, beta, out);
}